// Round 1
// baseline (276.433 us; speedup 1.0000x reference)
//
#include <hip/hip_runtime.h>

#define DDIM 128
#define RDIM 32
#define TILE 64
#define BLK  256
#define XPAD 132   // floats per x-tile row (pad vs 128 to break bank aliasing)
#define W2PAD 132  // w2 row stride in LDS
#define HPAD 36    // h-tile row stride

__device__ __forceinline__ float tanh_fast(float v) {
  float e = __expf(2.f * v);           // v>=~44 -> inf -> 1-0 = 1; v<<0 -> 0 -> -1
  return 1.f - 2.f / (e + 1.f);
}
__device__ __forceinline__ float sigmoid_fast(float v) {
  return 1.f / (1.f + __expf(-v));
}
__device__ __forceinline__ unsigned short f2bf(float f) {  // RNE f32->bf16
  unsigned u = __float_as_uint(f);
  u += 0x7fffu + ((u >> 16) & 1u);
  return (unsigned short)(u >> 16);
}
__device__ __forceinline__ float bf2f(unsigned short s) {
  return __uint_as_float(((unsigned)s) << 16);
}
__device__ __forceinline__ int lower_bound(const int* __restrict__ b, int n, int v) {
  int lo = 0, hi = n;
  while (lo < hi) { int m = (lo + hi) >> 1; if (b[m] < v) lo = m + 1; else hi = m; }
  return lo;
}

// ---------------------------------------------------------------------------
// K1: per-node MLP gate.  x2 = x * (1 + tanh(relu(x@W1+b1)@W2+b2))  -> bf16 ws
// Block = 256 threads, chunk = 256 nodes (4 tiles of 64).
// ---------------------------------------------------------------------------
__global__ __launch_bounds__(BLK, 2) void k1_mlp(
    const float* __restrict__ x,
    const float* __restrict__ w1, const float* __restrict__ b1,
    const float* __restrict__ w2, const float* __restrict__ b2,
    unsigned short* __restrict__ x2, int N)
{
  __shared__ __align__(16) float xs[TILE * XPAD];     // 33.8 KB
  __shared__ __align__(16) float w1s[DDIM * RDIM];    // 16 KB   [d][r]
  __shared__ __align__(16) float w2s[RDIM * W2PAD];   // 16.9 KB [r][d]
  __shared__ __align__(16) float hs[TILE * HPAD];     // 9.2 KB
  __shared__ __align__(16) float b1s[RDIM];
  __shared__ __align__(16) float b2s[DDIM];

  const int t = threadIdx.x;

  // ---- stage weights (once per block) ----
  for (int i = t; i < DDIM * RDIM / 4; i += BLK)
    ((float4*)w1s)[i] = ((const float4*)w1)[i];
  for (int i = t; i < RDIM * DDIM / 4; i += BLK) {
    int r = i >> 5, dc = (i & 31) << 2;
    *(float4*)&w2s[r * W2PAD + dc] = ((const float4*)w2)[i];
  }
  if (t < RDIM) b1s[t] = b1[t];
  if (t < DDIM) b2s[t] = b2[t];

  const int base0 = blockIdx.x * 256;

  for (int tile = 0; tile < 4; ++tile) {
    const int base = base0 + tile * TILE;
    if (base >= N) break;
    const int cnt = min(TILE, N - base);

    __syncthreads();  // protect xs/hs reuse (also orders weight staging, tile 0)

    // ---- load x tile -> LDS (zero-fill OOB rows) ----
    #pragma unroll
    for (int k = 0; k < 8; ++k) {
      int idx4 = t + k * BLK;             // 0..2047 float4 slots
      int n = idx4 >> 5, d = (idx4 & 31) << 2;
      float4 v = make_float4(0.f, 0.f, 0.f, 0.f);
      if (n < cnt) v = *(const float4*)&x[(size_t)(base + n) * DDIM + d];
      *(float4*)&xs[n * XPAD + d] = v;
    }
    __syncthreads();

    // ---- phase B: h = relu(x@W1 + b1) ----
    {
      const int rg = t & 7;         // 4 r's: r0 = rg*4
      const int ns = t >> 3;        // node slot 0..31; nodes ns, ns+32
      float h0[4], h1[4];
      #pragma unroll
      for (int c = 0; c < 4; ++c) { h0[c] = b1s[rg * 4 + c]; h1[c] = h0[c]; }
      #pragma unroll 4
      for (int d0 = 0; d0 < DDIM; d0 += 4) {
        float4 xa4 = *(const float4*)&xs[ns * XPAD + d0];
        float4 xb4 = *(const float4*)&xs[(ns + 32) * XPAD + d0];
        float xa[4] = {xa4.x, xa4.y, xa4.z, xa4.w};
        float xb[4] = {xb4.x, xb4.y, xb4.z, xb4.w};
        #pragma unroll
        for (int j = 0; j < 4; ++j) {
          float4 w4 = *(const float4*)&w1s[(d0 + j) * RDIM + rg * 4];
          float wv[4] = {w4.x, w4.y, w4.z, w4.w};
          #pragma unroll
          for (int c = 0; c < 4; ++c) {
            h0[c] = fmaf(xa[j], wv[c], h0[c]);
            h1[c] = fmaf(xb[j], wv[c], h1[c]);
          }
        }
      }
      #pragma unroll
      for (int c = 0; c < 4; ++c) { h0[c] = fmaxf(h0[c], 0.f); h1[c] = fmaxf(h1[c], 0.f); }
      *(float4*)&hs[ns * HPAD + rg * 4]        = make_float4(h0[0], h0[1], h0[2], h0[3]);
      *(float4*)&hs[(ns + 32) * HPAD + rg * 4] = make_float4(h1[0], h1[1], h1[2], h1[3]);
    }
    __syncthreads();

    // ---- phase C: a = tanh(h@W2 + b2); x2 = x*(1+a) -> global bf16 ----
    {
      const int dg = t & 31;        // 4 d's: d0 = dg*4
      const int ns = t >> 5;        // 0..7; nodes ns + 8i
      float acc[8][4];
      #pragma unroll
      for (int i = 0; i < 8; ++i)
        #pragma unroll
        for (int c = 0; c < 4; ++c) acc[i][c] = b2s[dg * 4 + c];

      #pragma unroll 2
      for (int r0 = 0; r0 < RDIM; r0 += 4) {
        float wv[4][4];
        #pragma unroll
        for (int j = 0; j < 4; ++j) {
          float4 w4 = *(const float4*)&w2s[(r0 + j) * W2PAD + dg * 4];
          wv[j][0] = w4.x; wv[j][1] = w4.y; wv[j][2] = w4.z; wv[j][3] = w4.w;
        }
        #pragma unroll
        for (int i = 0; i < 8; ++i) {
          float4 h4 = *(const float4*)&hs[(ns + i * 8) * HPAD + r0];
          float hv[4] = {h4.x, h4.y, h4.z, h4.w};
          #pragma unroll
          for (int j = 0; j < 4; ++j)
            #pragma unroll
            for (int c = 0; c < 4; ++c)
              acc[i][c] = fmaf(hv[j], wv[j][c], acc[i][c]);
        }
      }

      #pragma unroll
      for (int i = 0; i < 8; ++i) {
        int n = ns + i * 8;
        if (n < cnt) {
          float4 x4 = *(const float4*)&xs[n * XPAD + dg * 4];
          float xv[4] = {x4.x, x4.y, x4.z, x4.w};
          ushort4 o;
          float a0 = tanh_fast(acc[i][0]);
          float a1 = tanh_fast(acc[i][1]);
          float a2 = tanh_fast(acc[i][2]);
          float a3 = tanh_fast(acc[i][3]);
          o.x = f2bf(xv[0] * (1.f + a0));
          o.y = f2bf(xv[1] * (1.f + a1));
          o.z = f2bf(xv[2] * (1.f + a2));
          o.w = f2bf(xv[3] * (1.f + a3));
          *(ushort4*)&x2[(size_t)(base + n) * DDIM + dg * 4] = o;
        }
      }
    }
  }
}

// ---------------------------------------------------------------------------
// K2: per-graph mean of x2 -> tg = tanh(mean @ W).  One block per graph.
// ---------------------------------------------------------------------------
__global__ void k2_mean_w(
    const unsigned short* __restrict__ x2, const int* __restrict__ batch,
    const float* __restrict__ W, float* __restrict__ tg, int N)
{
  __shared__ __align__(16) float part[8][132];
  __shared__ float meanv[DDIM];
  __shared__ int bounds[2];
  const int g = blockIdx.x, t = threadIdx.x;
  if (t == 0) bounds[0] = lower_bound(batch, N, g);
  if (t == 1) bounds[1] = lower_bound(batch, N, g + 1);
  __syncthreads();
  const int lo = bounds[0], hi = bounds[1];
  const int q = t & 31, s = t >> 5;

  float acc[4] = {0.f, 0.f, 0.f, 0.f};
  for (int n = lo + s; n < hi; n += 8) {
    ushort4 u = *(const ushort4*)&x2[(size_t)n * DDIM + q * 4];
    acc[0] += bf2f(u.x); acc[1] += bf2f(u.y); acc[2] += bf2f(u.z); acc[3] += bf2f(u.w);
  }
  *(float4*)&part[s][q * 4] = make_float4(acc[0], acc[1], acc[2], acc[3]);
  __syncthreads();

  if (t < DDIM) {
    float m = 0.f;
    #pragma unroll
    for (int s2 = 0; s2 < 8; ++s2) m += part[s2][t];
    float invc = (hi > lo) ? 1.f / (float)(hi - lo) : 0.f;
    meanv[t] = m * invc;
  }
  __syncthreads();

  if (t < DDIM) {
    float a = 0.f;
    #pragma unroll 8
    for (int k = 0; k < DDIM; ++k) a = fmaf(meanv[k], W[k * DDIM + t], a);
    tg[(size_t)g * DDIM + t] = tanh_fast(a);
  }
}

// ---------------------------------------------------------------------------
// K4: coefs = sigmoid(x2 . tg[g]); out[g] = sum coefs*x2.  One block per graph.
// ---------------------------------------------------------------------------
__global__ void k4_out(
    const unsigned short* __restrict__ x2, const int* __restrict__ batch,
    const float* __restrict__ tg, float* __restrict__ out, int N)
{
  __shared__ __align__(16) float part[8][132];
  __shared__ int bounds[2];
  const int g = blockIdx.x, t = threadIdx.x;
  if (t == 0) bounds[0] = lower_bound(batch, N, g);
  if (t == 1) bounds[1] = lower_bound(batch, N, g + 1);
  __syncthreads();
  const int lo = bounds[0], hi = bounds[1];
  const int q = t & 31, s = t >> 5;

  float4 tg4 = *(const float4*)&tg[(size_t)g * DDIM + q * 4];
  float tga[4] = {tg4.x, tg4.y, tg4.z, tg4.w};
  float acc[4] = {0.f, 0.f, 0.f, 0.f};

  for (int n = lo + s; n < hi; n += 8) {   // all 32 lanes of a shuffle group share n
    ushort4 u = *(const ushort4*)&x2[(size_t)n * DDIM + q * 4];
    float xv[4] = {bf2f(u.x), bf2f(u.y), bf2f(u.z), bf2f(u.w)};
    float p = xv[0] * tga[0] + xv[1] * tga[1] + xv[2] * tga[2] + xv[3] * tga[3];
    #pragma unroll
    for (int off = 16; off >= 1; off >>= 1) p += __shfl_xor(p, off, 64);
    float coef = sigmoid_fast(p);
    #pragma unroll
    for (int c = 0; c < 4; ++c) acc[c] = fmaf(coef, xv[c], acc[c]);
  }
  *(float4*)&part[s][q * 4] = make_float4(acc[0], acc[1], acc[2], acc[3]);
  __syncthreads();

  if (t < DDIM) {
    float m = 0.f;
    #pragma unroll
    for (int s2 = 0; s2 < 8; ++s2) m += part[s2][t];
    out[(size_t)g * DDIM + t] = m;
  }
}

// ---------------------------------------------------------------------------
extern "C" void kernel_launch(void* const* d_in, const int* in_sizes, int n_in,
                              void* d_out, int out_size, void* d_ws, size_t ws_size,
                              hipStream_t stream) {
  const float* x     = (const float*)d_in[0];
  const int*   batch = (const int*)d_in[1];
  // d_in[2] = size (scalar on device; G recovered from out_size)
  const float* w1 = (const float*)d_in[3];
  const float* b1 = (const float*)d_in[4];
  const float* w2 = (const float*)d_in[5];
  const float* b2 = (const float*)d_in[6];
  const float* W  = (const float*)d_in[7];
  float* out = (float*)d_out;

  const int N = in_sizes[0] / DDIM;
  const int G = out_size / DDIM;

  float* tg = (float*)d_ws;                                    // G*128 f32 (1 MB)
  unsigned short* x2 = (unsigned short*)((char*)d_ws + (size_t)G * DDIM * sizeof(float));
  (void)ws_size; (void)n_in;

  const int grid1 = (N + 255) / 256;
  hipLaunchKernelGGL(k1_mlp, dim3(grid1), dim3(BLK), 0, stream, x, w1, b1, w2, b2, x2, N);
  hipLaunchKernelGGL(k2_mean_w, dim3(G), dim3(BLK), 0, stream, x2, batch, W, tg, N);
  hipLaunchKernelGGL(k4_out, dim3(G), dim3(BLK), 0, stream, x2, batch, tg, out, N);
}

// Round 2
// 177.432 us; speedup vs baseline: 1.5580x; 1.5580x over previous
//
#include <hip/hip_runtime.h>

#define DDIM 128
#define RDIM 32
#define BLK  256

typedef __attribute__((ext_vector_type(8))) short bf16x8;
typedef __attribute__((ext_vector_type(4))) float f32x4;

__device__ __forceinline__ float tanh_fast(float v) {
  float e = __expf(2.f * v);           // v>>0 -> inf -> 1; v<<0 -> 0 -> -1
  return 1.f - 2.f / (e + 1.f);
}
__device__ __forceinline__ float sigmoid_fast(float v) {
  return 1.f / (1.f + __expf(-v));
}
__device__ __forceinline__ unsigned short f2bf(float f) {  // RNE f32->bf16
  unsigned u = __float_as_uint(f);
  u += 0x7fffu + ((u >> 16) & 1u);
  return (unsigned short)(u >> 16);
}
__device__ __forceinline__ float bf2f(unsigned short s) {
  return __uint_as_float(((unsigned)s) << 16);
}
__device__ __forceinline__ int lower_bound(const int* __restrict__ b, int n, int v) {
  int lo = 0, hi = n;
  while (lo < hi) { int m = (lo + hi) >> 1; if (b[m] < v) lo = m + 1; else hi = m; }
  return lo;
}

// ---------------------------------------------------------------------------
// K1 (MFMA): x2 = x * (1 + tanh(relu(x@W1+b1)@W2+b2)) -> bf16 ws
// Block = 256 thr = 4 waves; 128 nodes/block; each wave owns 32 nodes.
// Frag layouts (16x16x32 bf16): A row=l&15, k=(l>>4)*8+j (contig);
//                               B col=l&15, k=(l>>4)*8+j;
//                               C/D col=l&15, row=(l>>4)*4+reg.
// ---------------------------------------------------------------------------
__global__ __launch_bounds__(BLK, 3) void k1_mfma(
    const float* __restrict__ x,
    const float* __restrict__ w1, const float* __restrict__ b1,
    const float* __restrict__ w2, const float* __restrict__ b2,
    unsigned short* __restrict__ x2, int N)
{
  __shared__ unsigned short xs[128 * 136];   // bf16 x tile, 272B row stride (34816 B)
  __shared__ unsigned short hs[128 * 40];    // bf16 h tile, 80B row stride (10240 B)
  __shared__ unsigned short w2s[8 * 64 * 8]; // W2 B-frags [nt][lane][8] (8192 B)

  const int t  = threadIdx.x;
  const int l  = t & 63;
  const int wv = t >> 6;
  const int wbase = wv * 32;               // this wave's node offset in tile
  const int base  = blockIdx.x * 128;
  const int cnt   = min(128, N - base);
  const int lr = l & 15;                   // tile row / col selector
  const int lq = l >> 4;                   // quad 0..3

  // ---- build W2 B-fragments in LDS (f32 gathers, L2-resident) ----
  for (int i = t; i < 512; i += BLK) {
    int nt = i >> 6, ll = i & 63;
    int col = nt * 16 + (ll & 15);
    int k0  = (ll >> 4) * 8;
    #pragma unroll
    for (int j = 0; j < 8; ++j)
      w2s[i * 8 + j] = f2bf(w2[(k0 + j) * DDIM + col]);
  }

  // ---- W1 B-fragments to registers ----
  bf16x8 w1r[2][4];
  #pragma unroll
  for (int nt = 0; nt < 2; ++nt) {
    #pragma unroll
    for (int kk = 0; kk < 4; ++kk) {
      int col   = nt * 16 + lr;
      int kbase = kk * 32 + lq * 8;
      bf16x8 v;
      #pragma unroll
      for (int j = 0; j < 8; ++j)
        v[j] = (short)f2bf(w1[(kbase + j) * RDIM + col]);
      w1r[nt][kk] = v;
    }
  }

  float b1v[2], b2v[8];
  b1v[0] = b1[lr]; b1v[1] = b1[16 + lr];
  #pragma unroll
  for (int nt = 0; nt < 8; ++nt) b2v[nt] = b2[nt * 16 + lr];

  // ---- stage x tile: fp32 global -> bf16 LDS (coalesced float4) ----
  #pragma unroll
  for (int k = 0; k < 16; ++k) {
    int idx4 = t + k * BLK;                // 4096 float4 slots = 128 rows x 32
    int node = idx4 >> 5, c4 = idx4 & 31;
    float4 v = make_float4(0.f, 0.f, 0.f, 0.f);
    if (node < cnt) v = *(const float4*)&x[(size_t)(base + node) * DDIM + c4 * 4];
    ushort4 o;
    o.x = f2bf(v.x); o.y = f2bf(v.y); o.z = f2bf(v.z); o.w = f2bf(v.w);
    *(ushort4*)&xs[node * 136 + c4 * 4] = o;
  }
  __syncthreads();

  // ---- phase B: H = relu(X @ W1 + b1)  (2 Mtiles x 2 Ntiles x 4 Ksteps) ----
  f32x4 hacc[2][2];
  #pragma unroll
  for (int mt = 0; mt < 2; ++mt)
    #pragma unroll
    for (int nt = 0; nt < 2; ++nt)
      #pragma unroll
      for (int c = 0; c < 4; ++c) hacc[mt][nt][c] = b1v[nt];

  #pragma unroll
  for (int kk = 0; kk < 4; ++kk) {
    bf16x8 a0 = *(const bf16x8*)&xs[(wbase + lr)      * 136 + kk * 32 + lq * 8];
    bf16x8 a1 = *(const bf16x8*)&xs[(wbase + 16 + lr) * 136 + kk * 32 + lq * 8];
    hacc[0][0] = __builtin_amdgcn_mfma_f32_16x16x32_bf16(a0, w1r[0][kk], hacc[0][0], 0, 0, 0);
    hacc[0][1] = __builtin_amdgcn_mfma_f32_16x16x32_bf16(a0, w1r[1][kk], hacc[0][1], 0, 0, 0);
    hacc[1][0] = __builtin_amdgcn_mfma_f32_16x16x32_bf16(a1, w1r[0][kk], hacc[1][0], 0, 0, 0);
    hacc[1][1] = __builtin_amdgcn_mfma_f32_16x16x32_bf16(a1, w1r[1][kk], hacc[1][1], 0, 0, 0);
  }

  #pragma unroll
  for (int mt = 0; mt < 2; ++mt)
    #pragma unroll
    for (int nt = 0; nt < 2; ++nt)
      #pragma unroll
      for (int c = 0; c < 4; ++c) {
        int m = wbase + mt * 16 + lq * 4 + c;
        int r = nt * 16 + lr;
        hs[m * 40 + r] = f2bf(fmaxf(hacc[mt][nt][c], 0.f));
      }
  // (same-wave LDS RAW on hs; compiler inserts lgkmcnt)

  // ---- phase C: A2 = H @ W2 + b2  (2 Mtiles x 8 Ntiles x 1 Kstep) ----
  f32x4 cacc[2][8];
  #pragma unroll
  for (int mt = 0; mt < 2; ++mt)
    #pragma unroll
    for (int nt = 0; nt < 8; ++nt)
      #pragma unroll
      for (int c = 0; c < 4; ++c) cacc[mt][nt][c] = b2v[nt];

  bf16x8 ah0 = *(const bf16x8*)&hs[(wbase + lr)      * 40 + lq * 8];
  bf16x8 ah1 = *(const bf16x8*)&hs[(wbase + 16 + lr) * 40 + lq * 8];
  #pragma unroll
  for (int nt = 0; nt < 8; ++nt) {
    bf16x8 bw = *(const bf16x8*)&w2s[(nt * 64 + l) * 8];
    cacc[0][nt] = __builtin_amdgcn_mfma_f32_16x16x32_bf16(ah0, bw, cacc[0][nt], 0, 0, 0);
    cacc[1][nt] = __builtin_amdgcn_mfma_f32_16x16x32_bf16(ah1, bw, cacc[1][nt], 0, 0, 0);
  }

  // ---- epilogue: xs <- bf16( x * (1 + tanh(a)) ), in place ----
  #pragma unroll
  for (int mt = 0; mt < 2; ++mt)
    #pragma unroll
    for (int nt = 0; nt < 8; ++nt)
      #pragma unroll
      for (int c = 0; c < 4; ++c) {
        int m   = wbase + mt * 16 + lq * 4 + c;
        int col = nt * 16 + lr;
        int off = m * 136 + col;
        float a  = tanh_fast(cacc[mt][nt][c]);
        float xv = bf2f(xs[off]);
        xs[off]  = f2bf(xv * (1.f + a));
      }
  __syncthreads();

  // ---- coalesced bf16 store of x2 tile ----
  #pragma unroll
  for (int k = 0; k < 8; ++k) {
    int idx  = t + k * BLK;                // 2048 16B chunks = 128 rows x 16
    int node = idx >> 4, coff = (idx & 15) * 8;
    if (node < cnt)
      *(bf16x8*)&x2[(size_t)(base + node) * DDIM + coff] =
          *(const bf16x8*)&xs[node * 136 + coff];
  }
}

// ---------------------------------------------------------------------------
// K2: per-graph mean of x2 -> tg = tanh(mean @ W).  One block per graph.
// ---------------------------------------------------------------------------
__global__ void k2_mean_w(
    const unsigned short* __restrict__ x2, const int* __restrict__ batch,
    const float* __restrict__ W, float* __restrict__ tg, int N)
{
  __shared__ __align__(16) float part[8][132];
  __shared__ float meanv[DDIM];
  __shared__ int bounds[2];
  const int g = blockIdx.x, t = threadIdx.x;
  if (t == 0) bounds[0] = lower_bound(batch, N, g);
  if (t == 1) bounds[1] = lower_bound(batch, N, g + 1);
  __syncthreads();
  const int lo = bounds[0], hi = bounds[1];
  const int q = t & 31, s = t >> 5;

  float acc[4] = {0.f, 0.f, 0.f, 0.f};
  for (int n = lo + s; n < hi; n += 8) {
    ushort4 u = *(const ushort4*)&x2[(size_t)n * DDIM + q * 4];
    acc[0] += bf2f(u.x); acc[1] += bf2f(u.y); acc[2] += bf2f(u.z); acc[3] += bf2f(u.w);
  }
  *(float4*)&part[s][q * 4] = make_float4(acc[0], acc[1], acc[2], acc[3]);
  __syncthreads();

  if (t < DDIM) {
    float m = 0.f;
    #pragma unroll
    for (int s2 = 0; s2 < 8; ++s2) m += part[s2][t];
    float invc = (hi > lo) ? 1.f / (float)(hi - lo) : 0.f;
    meanv[t] = m * invc;
  }
  __syncthreads();

  if (t < DDIM) {
    float a = 0.f;
    #pragma unroll 8
    for (int k = 0; k < DDIM; ++k) a = fmaf(meanv[k], W[k * DDIM + t], a);
    tg[(size_t)g * DDIM + t] = tanh_fast(a);
  }
}

// ---------------------------------------------------------------------------
// K4: coefs = sigmoid(x2 . tg[g]); out[g] = sum coefs*x2.  One block per graph.
// ---------------------------------------------------------------------------
__global__ void k4_out(
    const unsigned short* __restrict__ x2, const int* __restrict__ batch,
    const float* __restrict__ tg, float* __restrict__ out, int N)
{
  __shared__ __align__(16) float part[8][132];
  __shared__ int bounds[2];
  const int g = blockIdx.x, t = threadIdx.x;
  if (t == 0) bounds[0] = lower_bound(batch, N, g);
  if (t == 1) bounds[1] = lower_bound(batch, N, g + 1);
  __syncthreads();
  const int lo = bounds[0], hi = bounds[1];
  const int q = t & 31, s = t >> 5;

  float4 tg4 = *(const float4*)&tg[(size_t)g * DDIM + q * 4];
  float tga[4] = {tg4.x, tg4.y, tg4.z, tg4.w};
  float acc[4] = {0.f, 0.f, 0.f, 0.f};

  for (int n = lo + s; n < hi; n += 8) {   // 32 lanes of a shuffle group share n
    ushort4 u = *(const ushort4*)&x2[(size_t)n * DDIM + q * 4];
    float xv[4] = {bf2f(u.x), bf2f(u.y), bf2f(u.z), bf2f(u.w)};
    float p = xv[0] * tga[0] + xv[1] * tga[1] + xv[2] * tga[2] + xv[3] * tga[3];
    #pragma unroll
    for (int off = 16; off >= 1; off >>= 1) p += __shfl_xor(p, off, 64);
    float coef = sigmoid_fast(p);
    #pragma unroll
    for (int c = 0; c < 4; ++c) acc[c] = fmaf(coef, xv[c], acc[c]);
  }
  *(float4*)&part[s][q * 4] = make_float4(acc[0], acc[1], acc[2], acc[3]);
  __syncthreads();

  if (t < DDIM) {
    float m = 0.f;
    #pragma unroll
    for (int s2 = 0; s2 < 8; ++s2) m += part[s2][t];
    out[(size_t)g * DDIM + t] = m;
  }
}

// ---------------------------------------------------------------------------
extern "C" void kernel_launch(void* const* d_in, const int* in_sizes, int n_in,
                              void* d_out, int out_size, void* d_ws, size_t ws_size,
                              hipStream_t stream) {
  const float* x     = (const float*)d_in[0];
  const int*   batch = (const int*)d_in[1];
  const float* w1 = (const float*)d_in[3];
  const float* b1 = (const float*)d_in[4];
  const float* w2 = (const float*)d_in[5];
  const float* b2 = (const float*)d_in[6];
  const float* W  = (const float*)d_in[7];
  float* out = (float*)d_out;

  const int N = in_sizes[0] / DDIM;
  const int G = out_size / DDIM;

  float* tg = (float*)d_ws;                                    // G*128 f32 (1 MB)
  unsigned short* x2 = (unsigned short*)((char*)d_ws + (size_t)G * DDIM * sizeof(float));
  (void)ws_size; (void)n_in;

  const int grid1 = (N + 127) / 128;
  hipLaunchKernelGGL(k1_mfma, dim3(grid1), dim3(BLK), 0, stream, x, w1, b1, w2, b2, x2, N);
  hipLaunchKernelGGL(k2_mean_w, dim3(G), dim3(BLK), 0, stream, x2, batch, W, tg, N);
  hipLaunchKernelGGL(k4_out, dim3(G), dim3(BLK), 0, stream, x2, batch, tg, out, N);
}